// Round 14
// baseline (639.078 us; speedup 1.0000x reference)
//
#include <hip/hip_runtime.h>
#include <stdint.h>

typedef __bf16 bf16;
typedef __bf16 bf16x8 __attribute__((ext_vector_type(8)));
typedef __bf16 bf16x4 __attribute__((ext_vector_type(4)));
typedef float f32x4 __attribute__((ext_vector_type(4)));

#define MFMA16(a, b, c) __builtin_amdgcn_mfma_f32_16x16x32_bf16(a, b, c, 0, 0, 0)

typedef const __attribute__((address_space(1))) uint32_t* gas_t;
typedef __attribute__((address_space(3))) uint32_t* las_t;

__device__ __forceinline__ void gload16(const void* g, void* l) {
  __builtin_amdgcn_global_load_lds((gas_t)g, (las_t)l, 16, 0, 0);
}

// ---------------------------------------------------------------------------
// 128x128xK GEMM core, 2-phase pipelined double-buffered LDS (R11-proven).
// ---------------------------------------------------------------------------
__device__ __forceinline__ void stage_tile(const bf16* __restrict__ A, int lda,
                                           const bf16* __restrict__ Bt, int ldb,
                                           int m0, int n0, int k0, bf16* Ad,
                                           bf16* Bd, int w, int r8, int cs) {
#pragma unroll
  for (int i = 0; i < 4; ++i) {
    const int ii = (w << 2) + i;     // instr index 0..15
    const int row = (ii << 3) + r8;  // 0..127
    gload16(A + (size_t)(m0 + row) * lda + k0 + (cs << 3), Ad + (ii << 9));
    gload16(Bt + (size_t)(n0 + row) * ldb + k0 + (cs << 3), Bd + (ii << 9));
  }
}

__device__ __forceinline__ void compute_tile(const bf16* As, const bf16* Bs,
                                             f32x4 (*acc)[4], int lane, int wm,
                                             int wn) {
#pragma unroll
  for (int kk = 0; kk < 2; ++kk) {
    bf16x8 af[4], bfr[4];
#pragma unroll
    for (int mi = 0; mi < 4; ++mi) {
      const int r = wm * 64 + mi * 16 + (lane & 15);
      const int ch = kk * 4 + (lane >> 4);
      af[mi] = *(const bf16x8*)((const char*)As + r * 128 + ((ch ^ (r & 7)) << 4));
    }
#pragma unroll
    for (int ni = 0; ni < 4; ++ni) {
      const int r = wn * 64 + ni * 16 + (lane & 15);
      const int ch = kk * 4 + (lane >> 4);
      bfr[ni] = *(const bf16x8*)((const char*)Bs + r * 128 + ((ch ^ (r & 7)) << 4));
    }
#pragma unroll
    for (int mi = 0; mi < 4; ++mi)
#pragma unroll
      for (int ni = 0; ni < 4; ++ni)
        acc[mi][ni] = MFMA16(af[mi], bfr[ni], acc[mi][ni]);
  }
}

__device__ __forceinline__ void gemm_core(const bf16* __restrict__ A, int lda,
                                          const bf16* __restrict__ Bt, int ldb,
                                          int nk, int m0, int n0,
                                          bf16 (*smem)[128 * 64],
                                          f32x4 (*acc)[4]) {
  const int t = threadIdx.x;
  const int lane = t & 63, w = t >> 6;
  const int wm = w >> 1, wn = w & 1;
  const int r8 = lane >> 3;
  const int cs = (lane & 7) ^ r8;

  stage_tile(A, lda, Bt, ldb, m0, n0, 0, smem[0], smem[2], w, r8, cs);
  __syncthreads();
  int cur = 0;
  for (int kt = 0; kt < nk; ++kt) {
    if (kt + 1 < nk)
      stage_tile(A, lda, Bt, ldb, m0, n0, (kt + 1) << 6, smem[cur ^ 1],
                 smem[2 + (cur ^ 1)], w, r8, cs);
    compute_tile(smem[cur], smem[2 + cur], acc, lane, wm, wn);
    __syncthreads();
    cur ^= 1;
  }
}

// ---------------------------------------------------------------------------
// Epilogue transpose through LDS (4x16KB fp32 XOR-swizzled, one barrier).
// ---------------------------------------------------------------------------
__device__ __forceinline__ void epi_put(float* lds, const f32x4* accmi,
                                        int lane, int wm, int wn) {
#pragma unroll
  for (int ni = 0; ni < 4; ++ni) {
    const int c = wn * 64 + ni * 16 + (lane & 15);
    const int lr0 = wm * 16 + ((lane >> 4) << 2);
#pragma unroll
    for (int r = 0; r < 4; ++r) {
      const int lr = lr0 + r;
      lds[(lr << 7) + ((((c >> 2) ^ (lr & 7)) << 2) | (c & 3))] = accmi[ni][r];
    }
  }
}

__device__ __forceinline__ void epi_get(const float* lds, int t, f32x4* v) {
  const int lr = t >> 3, ch0 = (t & 7) << 2;
#pragma unroll
  for (int j = 0; j < 4; ++j)
    v[j] = *(const f32x4*)(lds + (lr << 7) + (((ch0 + j) ^ (lr & 7)) << 2));
}

// ---------------------------------------------------------------------------
// Weight transposes (one launch). out[n][k] = (bf16) in[k][n].
// ---------------------------------------------------------------------------
__global__ __launch_bounds__(256) void transpose_all(
    const float* __restrict__ Ws, const float* __restrict__ Wm,
    const float* __restrict__ Wl, const float* __restrict__ Wo,
    bf16* __restrict__ os, bf16* __restrict__ om, bf16* __restrict__ ol,
    bf16* __restrict__ oo) {
  __shared__ float tile[32][33];
  const int id = blockIdx.x;
  const float* in;
  bf16* outp;
  int N, bx;
  if (id < 768) { in = Ws; outp = os; N = 1536; bx = id; }
  else if (id < 1536) { in = Wm; outp = om; N = 1536; bx = id - 768; }
  else if (id < 2304) { in = Wl; outp = ol; N = 1536; bx = id - 1536; }
  else { in = Wo; outp = oo; N = 512; bx = id - 2304; }
  const int nbx = N >> 5;
  const int n0 = (bx % nbx) * 32, k0 = (bx / nbx) * 32;
  const int tx = threadIdx.x, ty = threadIdx.y;
#pragma unroll
  for (int i = 0; i < 4; ++i)
    tile[ty * 4 + i][tx] = in[(size_t)(k0 + ty * 4 + i) * N + n0 + tx];
  __syncthreads();
#pragma unroll
  for (int i = 0; i < 4; ++i)
    outp[(size_t)(n0 + ty * 4 + i) * 512 + k0 + tx] = (bf16)tile[tx][ty * 4 + i];
}

// ---------------------------------------------------------------------------
// Convert V columns of Wqkv (cols 1024..1535) to bf16 row-major Bv[k][j].
// grid 768 (256/scale), 256 thr, 4 elems/thr.
// ---------------------------------------------------------------------------
__global__ __launch_bounds__(256) void conv_v(const float* __restrict__ Ws,
                                              const float* __restrict__ Wm,
                                              const float* __restrict__ Wl,
                                              bf16* __restrict__ Bs,
                                              bf16* __restrict__ Bm,
                                              bf16* __restrict__ Bl) {
  int id = blockIdx.x;
  const float* W;
  bf16* B;
  if (id < 256) { W = Ws; B = Bs; }
  else if (id < 512) { W = Wm; B = Bm; id -= 256; }
  else { W = Wl; B = Bl; id -= 512; }
  const int idx = (id * 256 + threadIdx.x) * 4;
  const int k = idx >> 9, j = idx & 511;
  float4 v = *(const float4*)(W + (size_t)k * 1536 + 1024 + j);
  bf16x4 o = {(bf16)v.x, (bf16)v.y, (bf16)v.z, (bf16)v.w};
  *(bf16x4*)(B + idx) = o;
}

// ---------------------------------------------------------------------------
// wprep: (Wv')^T[m][k] = sum_n Wout[n][m] * Wv[k][n]  via gemm_core with
// A = wt_o (wt_o[m][n] = Wout[n][m]) and Bt = Bv (Bv[k][n] = Wv[k][n]).
// Overwrites wt_{s,m,l} rows 1024..1535. grid 48 (16/scale).
// ---------------------------------------------------------------------------
__global__ __launch_bounds__(256) void wprep(const bf16* __restrict__ wto,
                                             const bf16* __restrict__ Bs,
                                             const bf16* __restrict__ Bm,
                                             const bf16* __restrict__ Bl,
                                             bf16* __restrict__ ws_,
                                             bf16* __restrict__ wm_,
                                             bf16* __restrict__ wl_) {
  __shared__ bf16 smem[4][128 * 64];
  const int t = threadIdx.x, lane = t & 63, w = t >> 6;
  const int wm = w >> 1, wn = w & 1;
  const int id = blockIdx.x;
  const int sc = id >> 4, rem = id & 15;
  const bf16* Bv;
  bf16* dst;
  if (sc == 0) { Bv = Bs; dst = ws_; }
  else if (sc == 1) { Bv = Bm; dst = wm_; }
  else { Bv = Bl; dst = wl_; }
  dst += 1024 * 512;
  const int m0 = (rem >> 2) << 7, n0 = (rem & 3) << 7;

  f32x4 acc[4][4];
#pragma unroll
  for (int i = 0; i < 4; ++i)
#pragma unroll
    for (int j = 0; j < 4; ++j) acc[i][j] = (f32x4)0.0f;

  gemm_core(wto, 512, Bv, 512, 8, m0, n0, smem, acc);

  float* et = (float*)smem;
#pragma unroll
  for (int mi = 0; mi < 4; ++mi) epi_put(et + (mi << 12), acc[mi], lane, wm, wn);
  __syncthreads();
  const int lr = t >> 3, c0l = (t & 7) << 4;
#pragma unroll
  for (int mi = 0; mi < 4; ++mi) {
    f32x4 v[4];
    epi_get(et + (mi << 12), t, v);
    const int grow = m0 + ((lr >> 4) << 6) + mi * 16 + (lr & 15);
    bf16x8 o0, o1;
#pragma unroll
    for (int j = 0; j < 4; ++j)
#pragma unroll
      for (int k = 0; k < 4; ++k) {
        const bf16 val = (bf16)v[j][k];
        if (j < 2) o0[j * 4 + k] = val;
        else o1[(j - 2) * 4 + k] = val;
      }
    bf16* d = dst + (size_t)grow * 512 + n0 + c0l;
    *(bf16x8*)d = o0;
    *(bf16x8*)(d + 8) = o1;
  }
}

// ---------------------------------------------------------------------------
// bias_prep: pb[0..1023] = bq[0..1023]; pb[1024+m] = sum_n bq[1024+n]*Wout[n][m]
// grid 3 (scale), 512 threads.
// ---------------------------------------------------------------------------
__global__ __launch_bounds__(512) void bias_prep(const float* __restrict__ bs,
                                                 const float* __restrict__ bm,
                                                 const float* __restrict__ bl,
                                                 const float* __restrict__ Wout,
                                                 float* __restrict__ ps,
                                                 float* __restrict__ pm,
                                                 float* __restrict__ pl) {
  const float* b;
  float* p;
  if (blockIdx.x == 0) { b = bs; p = ps; }
  else if (blockIdx.x == 1) { b = bm; p = pm; }
  else { b = bl; p = pl; }
  const int t = threadIdx.x;
  p[t] = b[t];
  p[512 + t] = b[512 + t];
  float acc = 0.0f;
  for (int n = 0; n < 512; ++n) acc += b[1024 + n] * Wout[(size_t)n * 512 + t];
  p[1024 + t] = acc;
}

// ---------------------------------------------------------------------------
// LayerNorm -> h bf16 (scale-contiguous row blocks)
// ---------------------------------------------------------------------------
__global__ __launch_bounds__(256) void ln_kernel(const float* __restrict__ x,
                                                 const float* __restrict__ gamma,
                                                 const float* __restrict__ beta,
                                                 bf16* __restrict__ h) {
  const int t = threadIdx.x, lane = t & 63, w = t >> 6;
  const int row = blockIdx.x * 4 + w;
  const float* xr = x + (size_t)row * 512 + lane * 8;
  float4 v0 = *(const float4*)xr;
  float4 v1 = *(const float4*)(xr + 4);
  float s = v0.x + v0.y + v0.z + v0.w + v1.x + v1.y + v1.z + v1.w;
  float q = v0.x * v0.x + v0.y * v0.y + v0.z * v0.z + v0.w * v0.w +
            v1.x * v1.x + v1.y * v1.y + v1.z * v1.z + v1.w * v1.w;
#pragma unroll
  for (int off = 1; off < 64; off <<= 1) {
    s += __shfl_xor(s, off);
    q += __shfl_xor(q, off);
  }
  const float mean = s * (1.0f / 512.0f);
  const float var = q * (1.0f / 512.0f) - mean * mean;
  const float rs = rsqrtf(var + 1e-5f);
  float4 g0 = *(const float4*)(gamma + lane * 8);
  float4 g1 = *(const float4*)(gamma + lane * 8 + 4);
  float4 b0 = *(const float4*)(beta + lane * 8);
  float4 b1 = *(const float4*)(beta + lane * 8 + 4);
  const int bb = row / 3584;
  const int sp = row - bb * 3584;
  size_t drow;
  if (sp < 512)
    drow = (size_t)bb * 512 + sp;
  else if (sp < 1536)
    drow = 8192 + (size_t)bb * 1024 + (sp - 512);
  else
    drow = 24576 + (size_t)bb * 2048 + (sp - 1536);
  bf16x8 ov = {(bf16)((v0.x - mean) * rs * g0.x + b0.x),
               (bf16)((v0.y - mean) * rs * g0.y + b0.y),
               (bf16)((v0.z - mean) * rs * g0.z + b0.z),
               (bf16)((v0.w - mean) * rs * g0.w + b0.w),
               (bf16)((v1.x - mean) * rs * g1.x + b1.x),
               (bf16)((v1.y - mean) * rs * g1.y + b1.y),
               (bf16)((v1.z - mean) * rs * g1.z + b1.z),
               (bf16)((v1.w - mean) * rs * g1.w + b1.w)};
  *(bf16x8*)(h + drow * 512 + lane * 8) = ov;
}

// ---------------------------------------------------------------------------
// QKV GEMM body. n-tiles 0..7 -> Q/K (qk stride 1024); 8..11 -> V' (vt
// transposed per batch). Uses prepared bias (V part = bv').
// ---------------------------------------------------------------------------
__device__ __forceinline__ void qkv_body(const bf16* __restrict__ A,
                                         const bf16* __restrict__ Bt,
                                         const float* __restrict__ bias,
                                         bf16* __restrict__ qk,
                                         bf16* __restrict__ vt, int l2L,
                                         int lgs, bf16 (*smem)[128 * 64]) {
  const int t = threadIdx.x, lane = t & 63, w = t >> 6;
  const int wm = w >> 1, wn = w & 1;
  const int m0 = (lgs / 12) << 7;
  const int n0 = (lgs % 12) << 7;
  const int L = 1 << l2L;

  f32x4 acc[4][4];
#pragma unroll
  for (int i = 0; i < 4; ++i)
#pragma unroll
    for (int j = 0; j < 4; ++j) acc[i][j] = (f32x4)0.0f;

  gemm_core(A, 512, Bt, 512, 8, m0, n0, smem, acc);

  if (n0 < 1024) {
    float* et = (float*)smem;
#pragma unroll
    for (int mi = 0; mi < 4; ++mi) epi_put(et + (mi << 12), acc[mi], lane, wm, wn);
    __syncthreads();
    const int lr = t >> 3, c0l = (t & 7) << 4;
    const int gcol = n0 + c0l;
#pragma unroll
    for (int mi = 0; mi < 4; ++mi) {
      f32x4 v[4];
      epi_get(et + (mi << 12), t, v);
      const int grow = m0 + ((lr >> 4) << 6) + mi * 16 + (lr & 15);
      bf16x8 o0, o1;
#pragma unroll
      for (int j = 0; j < 4; ++j) {
        float4 bv = *(const float4*)(bias + gcol + j * 4);
#pragma unroll
        for (int k = 0; k < 4; ++k) {
          const bf16 val = (bf16)(v[j][k] + ((const float*)&bv)[k]);
          if (j < 2) o0[j * 4 + k] = val;
          else o1[(j - 2) * 4 + k] = val;
        }
      }
      bf16* dst = qk + (size_t)grow * 1024 + gcol;
      *(bf16x8*)dst = o0;
      *(bf16x8*)(dst + 8) = o1;
    }
  } else {
#pragma unroll
    for (int ni = 0; ni < 4; ++ni) {
      const int col = n0 + wn * 64 + ni * 16 + (lane & 15);
      const float bv = bias[col];
#pragma unroll
      for (int mi = 0; mi < 4; ++mi) {
        const int rb = m0 + wm * 64 + mi * 16 + ((lane >> 4) << 2);
        const int d = col - 1024;
        const int bi = rb >> l2L;
        const int kv = rb & (L - 1);
        bf16x4 pk = {(bf16)(acc[mi][ni][0] + bv), (bf16)(acc[mi][ni][1] + bv),
                     (bf16)(acc[mi][ni][2] + bv), (bf16)(acc[mi][ni][3] + bv)};
        *(bf16x4*)(vt + ((size_t)bi * 512 + d) * L + kv) = pk;
      }
    }
  }
}

// Merged QKV: S (768) + M (1536) + L (3072) = 5376 blocks.
__global__ __launch_bounds__(256) void qkv_all(
    const bf16* __restrict__ h, const bf16* __restrict__ wt_s,
    const bf16* __restrict__ wt_m, const bf16* __restrict__ wt_l,
    const float* __restrict__ pb_s, const float* __restrict__ pb_m,
    const float* __restrict__ pb_l, bf16* __restrict__ qk,
    bf16* __restrict__ vt) {
  __shared__ bf16 smem[4][128 * 64];
  const int lg = (blockIdx.x & 7) * (5376 >> 3) + (blockIdx.x >> 3);
  if (lg < 768) {
    qkv_body(h, wt_s, pb_s, qk, vt, 9, lg, smem);
  } else if (lg < 2304) {
    qkv_body(h + 8192ull * 512, wt_m, pb_m, qk + 8192ull * 1024,
             vt + 4194304ull, 10, lg - 768, smem);
  } else {
    qkv_body(h + 24576ull * 512, wt_l, pb_l, qk + 24576ull * 1024,
             vt + 12582912ull, 11, lg - 2304, smem);
  }
}

// ---------------------------------------------------------------------------
// sgemm: P = exp2(S*scale*log2e) -> Pbuf + deterministic per-(row, n-tile)
// partial sums into psum (no atomics; max-subtraction safe to skip).
// ---------------------------------------------------------------------------
__global__ __launch_bounds__(256) void sgemm_one(const bf16* __restrict__ qkp,
                                                 bf16* __restrict__ Cb, int l2L,
                                                 int b0, float scl2, int nblk,
                                                 float* __restrict__ psum) {
  __shared__ bf16 smem[4][128 * 64];
  const int t = threadIdx.x, lane = t & 63, w = t >> 6;
  const int wm = w >> 1, wn = w & 1;
  const int L = 1 << l2L;
  const int l2nt = l2L - 7;
  const int lgs = (blockIdx.x & 7) * (nblk >> 3) + (blockIdx.x >> 3);
  const int bi = lgs >> (2 * l2nt);
  const int rem = lgs & ((1 << (2 * l2nt)) - 1);
  const int m0 = (rem >> l2nt) << 7;
  const int n0 = (rem & ((1 << l2nt) - 1)) << 7;

  const bf16* Ab = qkp + (size_t)(b0 + bi) * L * 1024;
  const bf16* Bb = Ab + 512;
  bf16* C = Cb + (size_t)bi * L * L;

  f32x4 acc[4][4];
#pragma unroll
  for (int i = 0; i < 4; ++i)
#pragma unroll
    for (int j = 0; j < 4; ++j) acc[i][j] = (f32x4)0.0f;

  gemm_core(Ab, 1024, Bb, 1024, 8, m0, n0, smem, acc);

  float* et = (float*)smem;
#pragma unroll
  for (int mi = 0; mi < 4; ++mi) epi_put(et + (mi << 12), acc[mi], lane, wm, wn);
  __syncthreads();
  const int lr = t >> 3, c0l = (t & 7) << 4;
  const int tilej = n0 >> 7;
#pragma unroll
  for (int mi = 0; mi < 4; ++mi) {
    f32x4 v[4];
    epi_get(et + (mi << 12), t, v);
    const int grow = m0 + ((lr >> 4) << 6) + mi * 16 + (lr & 15);
    bf16x8 o0, o1;
    float ps = 0.0f;
#pragma unroll
    for (int j = 0; j < 4; ++j)
#pragma unroll
      for (int k = 0; k < 4; ++k) {
        const float e = exp2f(v[j][k] * scl2);
        const bf16 val = (bf16)e;
        ps += (float)val;
        if (j < 2) o0[j * 4 + k] = val;
        else o1[(j - 2) * 4 + k] = val;
      }
    bf16* dst = C + (size_t)grow * L + n0 + c0l;
    *(bf16x8*)dst = o0;
    *(bf16x8*)(dst + 8) = o1;
    ps += __shfl_xor(ps, 1);
    ps += __shfl_xor(ps, 2);
    ps += __shfl_xor(ps, 4);
    if ((t & 7) == 0) psum[((size_t)(bi * L + grow) << 4) + tilej] = ps;
  }
}

// ---------------------------------------------------------------------------
// pv: out[g] = (P * V')/l + bout + x[g]  (fp32 direct to d_out).
// g = (b0+bi)*3584 + seqoff + grow. V' = V*Wout folded via wprep.
// ---------------------------------------------------------------------------
__global__ __launch_bounds__(256) void pv_one(const bf16* __restrict__ sb,
                                              const bf16* __restrict__ vtp,
                                              float* __restrict__ out,
                                              const float* __restrict__ x,
                                              const float* __restrict__ bout,
                                              int l2L, int b0, int seqoff,
                                              int nblk,
                                              const float* __restrict__ psum) {
  __shared__ bf16 smem[4][128 * 64];
  const int t = threadIdx.x, lane = t & 63, w = t >> 6;
  const int wm = w >> 1, wn = w & 1;
  const int L = 1 << l2L;
  const int l2nt = l2L - 7;
  const int ntile = 1 << l2nt;
  const int lgs = (blockIdx.x & 7) * (nblk >> 3) + (blockIdx.x >> 3);
  const int bi = lgs >> (l2nt + 2);
  const int rem = lgs & ((1 << (l2nt + 2)) - 1);
  const int m0 = (rem >> 2) << 7;
  const int n0 = (rem & 3) << 7;
  const int b = b0 + bi;

  const bf16* Ab = sb + (size_t)bi * L * L;
  const bf16* Bb = vtp + (size_t)b * 512 * L;

  f32x4 acc[4][4];
#pragma unroll
  for (int i = 0; i < 4; ++i)
#pragma unroll
    for (int j = 0; j < 4; ++j) acc[i][j] = (f32x4)0.0f;

  gemm_core(Ab, L, Bb, L, L >> 6, m0, n0, smem, acc);

  float* et = (float*)smem;
#pragma unroll
  for (int mi = 0; mi < 4; ++mi) epi_put(et + (mi << 12), acc[mi], lane, wm, wn);
  __syncthreads();
  const int lr = t >> 3, c0l = (t & 7) << 4;
  const int gcol = n0 + c0l;
  float4 bvv[4];
#pragma unroll
  for (int j = 0; j < 4; ++j) bvv[j] = *(const float4*)(bout + gcol + j * 4);
#pragma unroll
  for (int mi = 0; mi < 4; ++mi) {
    f32x4 v[4];
    epi_get(et + (mi << 12), t, v);
    const int grow = m0 + ((lr >> 4) << 6) + mi * 16 + (lr & 15);
    const float* pr = psum + ((size_t)(bi * L + grow) << 4);
    float rs = 0.0f;
    for (int j = 0; j < ntile; ++j) rs += pr[j];
    const float inv = 1.0f / rs;
    const size_t g = (size_t)b * 3584 + seqoff + grow;
    const float* xs = x + g * 512 + gcol;
    float* os = out + g * 512 + gcol;
#pragma unroll
    for (int j = 0; j < 4; ++j) {
      float4 xv = *(const float4*)(xs + j * 4);
      float4 ov;
      ov.x = v[j][0] * inv + bvv[j].x + xv.x;
      ov.y = v[j][1] * inv + bvv[j].y + xv.y;
      ov.z = v[j][2] * inv + bvv[j].z + xv.z;
      ov.w = v[j][3] * inv + bvv[j].w + xv.w;
      *(float4*)(os + j * 4) = ov;
    }
  }
}

// ---------------------------------------------------------------------------
extern "C" void kernel_launch(void* const* d_in, const int* in_sizes, int n_in,
                              void* d_out, int out_size, void* d_ws,
                              size_t ws_size, hipStream_t stream) {
  const float* x = (const float*)d_in[0];
  const float* gamma = (const float*)d_in[1];
  const float* beta = (const float*)d_in[2];
  const float* Wq_s = (const float*)d_in[3];
  const float* bq_s = (const float*)d_in[4];
  const float* Wq_m = (const float*)d_in[5];
  const float* bq_m = (const float*)d_in[6];
  const float* Wq_l = (const float*)d_in[7];
  const float* bq_l = (const float*)d_in[8];
  const float* Wout = (const float*)d_in[9];
  const float* bout = (const float*)d_in[10];
  float* out = (float*)d_out;

  char* ws = (char*)d_ws;
  bf16* h = (bf16*)(ws);                      // 57344 x 512 (later: P buffer)
  bf16* qk = (bf16*)(ws + 58720256ull);       // 57344 x 1024
  bf16* vt = (bf16*)(ws + 176160768ull);      // 57344 x 512 (V'^T per batch)
  bf16* wt_s = (bf16*)(ws + 234881024ull);
  bf16* wt_m = (bf16*)(ws + 236453888ull);
  bf16* wt_l = (bf16*)(ws + 238026752ull);
  bf16* wt_o = (bf16*)(ws + 239599616ull);
  float* psum = (float*)(ws + 240123904ull);  // 16384 rows x 16 x fp32 (1MB)

  // d_out tail scratch (dead before pv writes): Bv (bf16 V-cols) + prepared
  // biases. pv overwrites every element of d_out exactly once afterwards.
  char* od = (char*)d_out;
  bf16* Bv_s = (bf16*)(od + 110000128ull);   // 3 x 512KB
  bf16* Bv_m = Bv_s + 262144;
  bf16* Bv_l = Bv_m + 262144;
  float* pb_s = (float*)(od + 111573504ull);  // 3 x 1536 fp32
  float* pb_m = pb_s + 1536;
  float* pb_l = pb_m + 1536;

  transpose_all<<<2560, dim3(32, 8), 0, stream>>>(Wq_s, Wq_m, Wq_l, Wout, wt_s,
                                                  wt_m, wt_l, wt_o);
  conv_v<<<768, 256, 0, stream>>>(Wq_s, Wq_m, Wq_l, Bv_s, Bv_m, Bv_l);
  wprep<<<48, 256, 0, stream>>>(wt_o, Bv_s, Bv_m, Bv_l, wt_s, wt_m, wt_l);
  bias_prep<<<3, 512, 0, stream>>>(bq_s, bq_m, bq_l, Wout, pb_s, pb_m, pb_l);

  ln_kernel<<<14336, 256, 0, stream>>>(x, gamma, beta, h);

  qkv_all<<<5376, 256, 0, stream>>>(h, wt_s, wt_m, wt_l, pb_s, pb_m, pb_l, qk,
                                    vt);

  const float scale = 0.04419417382415922f;      // 512^-0.5
  const float scl2 = scale * 1.44269504088896f;  // * log2(e)
  bf16* P = h;  // h is dead after qkv_all; reuse as P buffer (58.7MB)

  // S: L=512, 16 batches (P = 8.4MB)
  sgemm_one<<<256, 256, 0, stream>>>(qk, P, 9, 0, scl2, 256, psum);
  pv_one<<<256, 256, 0, stream>>>(P, vt, out, x, bout, 9, 0, 0, 256, psum);

  // M: L=1024, 16 batches (P = 33.6MB)
  sgemm_one<<<1024, 256, 0, stream>>>(qk + 8192ull * 1024, P, 10, 0, scl2,
                                      1024, psum);
  pv_one<<<512, 256, 0, stream>>>(P, vt + 4194304ull, out, x, bout, 10, 0, 512,
                                  512, psum);

  // L: L=2048, four quarters of 4 batches (P = 33.6MB each)
  for (int q = 0; q < 4; ++q) {
    sgemm_one<<<1024, 256, 0, stream>>>(qk + 24576ull * 1024, P, 11, q * 4,
                                        scl2, 1024, psum);
    pv_one<<<256, 256, 0, stream>>>(P, vt + 12582912ull, out, x, bout, 11,
                                    q * 4, 1536, 256, psum);
  }
}

// Round 15
// 544.039 us; speedup vs baseline: 1.1747x; 1.1747x over previous
//
#include <hip/hip_runtime.h>
#include <stdint.h>

typedef __bf16 bf16;
typedef __bf16 bf16x8 __attribute__((ext_vector_type(8)));
typedef __bf16 bf16x4 __attribute__((ext_vector_type(4)));
typedef float f32x4 __attribute__((ext_vector_type(4)));

#define MFMA16(a, b, c) __builtin_amdgcn_mfma_f32_16x16x32_bf16(a, b, c, 0, 0, 0)

typedef const __attribute__((address_space(1))) uint32_t* gas_t;
typedef __attribute__((address_space(3))) uint32_t* las_t;

__device__ __forceinline__ void gload16(const void* g, void* l) {
  __builtin_amdgcn_global_load_lds((gas_t)g, (las_t)l, 16, 0, 0);
}

// ---------------------------------------------------------------------------
// 128x128xK GEMM core, 2-phase pipelined double-buffered LDS (R11-proven).
// ---------------------------------------------------------------------------
__device__ __forceinline__ void stage_tile(const bf16* __restrict__ A, int lda,
                                           const bf16* __restrict__ Bt, int ldb,
                                           int m0, int n0, int k0, bf16* Ad,
                                           bf16* Bd, int w, int r8, int cs) {
#pragma unroll
  for (int i = 0; i < 4; ++i) {
    const int ii = (w << 2) + i;     // instr index 0..15
    const int row = (ii << 3) + r8;  // 0..127
    gload16(A + (size_t)(m0 + row) * lda + k0 + (cs << 3), Ad + (ii << 9));
    gload16(Bt + (size_t)(n0 + row) * ldb + k0 + (cs << 3), Bd + (ii << 9));
  }
}

__device__ __forceinline__ void compute_tile(const bf16* As, const bf16* Bs,
                                             f32x4 (*acc)[4], int lane, int wm,
                                             int wn) {
#pragma unroll
  for (int kk = 0; kk < 2; ++kk) {
    bf16x8 af[4], bfr[4];
#pragma unroll
    for (int mi = 0; mi < 4; ++mi) {
      const int r = wm * 64 + mi * 16 + (lane & 15);
      const int ch = kk * 4 + (lane >> 4);
      af[mi] = *(const bf16x8*)((const char*)As + r * 128 + ((ch ^ (r & 7)) << 4));
    }
#pragma unroll
    for (int ni = 0; ni < 4; ++ni) {
      const int r = wn * 64 + ni * 16 + (lane & 15);
      const int ch = kk * 4 + (lane >> 4);
      bfr[ni] = *(const bf16x8*)((const char*)Bs + r * 128 + ((ch ^ (r & 7)) << 4));
    }
#pragma unroll
    for (int mi = 0; mi < 4; ++mi)
#pragma unroll
      for (int ni = 0; ni < 4; ++ni)
        acc[mi][ni] = MFMA16(af[mi], bfr[ni], acc[mi][ni]);
  }
}

__device__ __forceinline__ void gemm_core(const bf16* __restrict__ A, int lda,
                                          const bf16* __restrict__ Bt, int ldb,
                                          int nk, int m0, int n0,
                                          bf16 (*smem)[128 * 64],
                                          f32x4 (*acc)[4]) {
  const int t = threadIdx.x;
  const int lane = t & 63, w = t >> 6;
  const int wm = w >> 1, wn = w & 1;
  const int r8 = lane >> 3;
  const int cs = (lane & 7) ^ r8;

  stage_tile(A, lda, Bt, ldb, m0, n0, 0, smem[0], smem[2], w, r8, cs);
  __syncthreads();
  int cur = 0;
  for (int kt = 0; kt < nk; ++kt) {
    if (kt + 1 < nk)
      stage_tile(A, lda, Bt, ldb, m0, n0, (kt + 1) << 6, smem[cur ^ 1],
                 smem[2 + (cur ^ 1)], w, r8, cs);
    compute_tile(smem[cur], smem[2 + cur], acc, lane, wm, wn);
    __syncthreads();
    cur ^= 1;
  }
}

// ---------------------------------------------------------------------------
// Epilogue transpose through LDS (4x16KB fp32 XOR-swizzled, one barrier).
// ---------------------------------------------------------------------------
__device__ __forceinline__ void epi_put(float* lds, const f32x4* accmi,
                                        int lane, int wm, int wn) {
#pragma unroll
  for (int ni = 0; ni < 4; ++ni) {
    const int c = wn * 64 + ni * 16 + (lane & 15);
    const int lr0 = wm * 16 + ((lane >> 4) << 2);
#pragma unroll
    for (int r = 0; r < 4; ++r) {
      const int lr = lr0 + r;
      lds[(lr << 7) + ((((c >> 2) ^ (lr & 7)) << 2) | (c & 3))] = accmi[ni][r];
    }
  }
}

__device__ __forceinline__ void epi_get(const float* lds, int t, f32x4* v) {
  const int lr = t >> 3, ch0 = (t & 7) << 2;
#pragma unroll
  for (int j = 0; j < 4; ++j)
    v[j] = *(const f32x4*)(lds + (lr << 7) + (((ch0 + j) ^ (lr & 7)) << 2));
}

// ---------------------------------------------------------------------------
// Weight transposes (one launch). out[n][k] = (bf16) in[k][n].
// ---------------------------------------------------------------------------
__global__ __launch_bounds__(256) void transpose_all(
    const float* __restrict__ Ws, const float* __restrict__ Wm,
    const float* __restrict__ Wl, const float* __restrict__ Wo,
    bf16* __restrict__ os, bf16* __restrict__ om, bf16* __restrict__ ol,
    bf16* __restrict__ oo) {
  __shared__ float tile[32][33];
  const int id = blockIdx.x;
  const float* in;
  bf16* outp;
  int N, bx;
  if (id < 768) { in = Ws; outp = os; N = 1536; bx = id; }
  else if (id < 1536) { in = Wm; outp = om; N = 1536; bx = id - 768; }
  else if (id < 2304) { in = Wl; outp = ol; N = 1536; bx = id - 1536; }
  else { in = Wo; outp = oo; N = 512; bx = id - 2304; }
  const int nbx = N >> 5;
  const int n0 = (bx % nbx) * 32, k0 = (bx / nbx) * 32;
  const int tx = threadIdx.x, ty = threadIdx.y;
#pragma unroll
  for (int i = 0; i < 4; ++i)
    tile[ty * 4 + i][tx] = in[(size_t)(k0 + ty * 4 + i) * N + n0 + tx];
  __syncthreads();
#pragma unroll
  for (int i = 0; i < 4; ++i)
    outp[(size_t)(n0 + ty * 4 + i) * 512 + k0 + tx] = (bf16)tile[tx][ty * 4 + i];
}

// ---------------------------------------------------------------------------
// Convert V columns of Wqkv (cols 1024..1535) to bf16 row-major Bv[k][j].
// ---------------------------------------------------------------------------
__global__ __launch_bounds__(256) void conv_v(const float* __restrict__ Ws,
                                              const float* __restrict__ Wm,
                                              const float* __restrict__ Wl,
                                              bf16* __restrict__ Bs,
                                              bf16* __restrict__ Bm,
                                              bf16* __restrict__ Bl) {
  int id = blockIdx.x;
  const float* W;
  bf16* B;
  if (id < 256) { W = Ws; B = Bs; }
  else if (id < 512) { W = Wm; B = Bm; id -= 256; }
  else { W = Wl; B = Bl; id -= 512; }
  const int idx = (id * 256 + threadIdx.x) * 4;
  const int k = idx >> 9, j = idx & 511;
  float4 v = *(const float4*)(W + (size_t)k * 1536 + 1024 + j);
  bf16x4 o = {(bf16)v.x, (bf16)v.y, (bf16)v.z, (bf16)v.w};
  *(bf16x4*)(B + idx) = o;
}

// ---------------------------------------------------------------------------
// wprep: (Wv')^T[m][k] = sum_n Wout[n][m] * Wv[k][n] -> wt rows 1024..1535.
// ---------------------------------------------------------------------------
__global__ __launch_bounds__(256) void wprep(const bf16* __restrict__ wto,
                                             const bf16* __restrict__ Bs,
                                             const bf16* __restrict__ Bm,
                                             const bf16* __restrict__ Bl,
                                             bf16* __restrict__ ws_,
                                             bf16* __restrict__ wm_,
                                             bf16* __restrict__ wl_) {
  __shared__ bf16 smem[4][128 * 64];
  const int t = threadIdx.x, lane = t & 63, w = t >> 6;
  const int wm = w >> 1, wn = w & 1;
  const int id = blockIdx.x;
  const int sc = id >> 4, rem = id & 15;
  const bf16* Bv;
  bf16* dst;
  if (sc == 0) { Bv = Bs; dst = ws_; }
  else if (sc == 1) { Bv = Bm; dst = wm_; }
  else { Bv = Bl; dst = wl_; }
  dst += 1024 * 512;
  const int m0 = (rem >> 2) << 7, n0 = (rem & 3) << 7;

  f32x4 acc[4][4];
#pragma unroll
  for (int i = 0; i < 4; ++i)
#pragma unroll
    for (int j = 0; j < 4; ++j) acc[i][j] = (f32x4)0.0f;

  gemm_core(wto, 512, Bv, 512, 8, m0, n0, smem, acc);

  float* et = (float*)smem;
#pragma unroll
  for (int mi = 0; mi < 4; ++mi) epi_put(et + (mi << 12), acc[mi], lane, wm, wn);
  __syncthreads();
  const int lr = t >> 3, c0l = (t & 7) << 4;
#pragma unroll
  for (int mi = 0; mi < 4; ++mi) {
    f32x4 v[4];
    epi_get(et + (mi << 12), t, v);
    const int grow = m0 + ((lr >> 4) << 6) + mi * 16 + (lr & 15);
    bf16x8 o0, o1;
#pragma unroll
    for (int j = 0; j < 4; ++j)
#pragma unroll
      for (int k = 0; k < 4; ++k) {
        const bf16 val = (bf16)v[j][k];
        if (j < 2) o0[j * 4 + k] = val;
        else o1[(j - 2) * 4 + k] = val;
      }
    bf16* d = dst + (size_t)grow * 512 + n0 + c0l;
    *(bf16x8*)d = o0;
    *(bf16x8*)(d + 8) = o1;
  }
}

// ---------------------------------------------------------------------------
// bias_prep: pb[0..1023] = bq[0..1023]; pb[1024+m] = sum_n bq[1024+n]*Wout[n][m]
// ---------------------------------------------------------------------------
__global__ __launch_bounds__(512) void bias_prep(const float* __restrict__ bs,
                                                 const float* __restrict__ bm,
                                                 const float* __restrict__ bl,
                                                 const float* __restrict__ Wout,
                                                 float* __restrict__ ps,
                                                 float* __restrict__ pm,
                                                 float* __restrict__ pl) {
  const float* b;
  float* p;
  if (blockIdx.x == 0) { b = bs; p = ps; }
  else if (blockIdx.x == 1) { b = bm; p = pm; }
  else { b = bl; p = pl; }
  const int t = threadIdx.x;
  p[t] = b[t];
  p[512 + t] = b[512 + t];
  float acc = 0.0f;
  for (int n = 0; n < 512; ++n) acc += b[1024 + n] * Wout[(size_t)n * 512 + t];
  p[1024 + t] = acc;
}

// ---------------------------------------------------------------------------
// LayerNorm -> h bf16 (scale-contiguous row blocks)
// ---------------------------------------------------------------------------
__global__ __launch_bounds__(256) void ln_kernel(const float* __restrict__ x,
                                                 const float* __restrict__ gamma,
                                                 const float* __restrict__ beta,
                                                 bf16* __restrict__ h) {
  const int t = threadIdx.x, lane = t & 63, w = t >> 6;
  const int row = blockIdx.x * 4 + w;
  const float* xr = x + (size_t)row * 512 + lane * 8;
  float4 v0 = *(const float4*)xr;
  float4 v1 = *(const float4*)(xr + 4);
  float s = v0.x + v0.y + v0.z + v0.w + v1.x + v1.y + v1.z + v1.w;
  float q = v0.x * v0.x + v0.y * v0.y + v0.z * v0.z + v0.w * v0.w +
            v1.x * v1.x + v1.y * v1.y + v1.z * v1.z + v1.w * v1.w;
#pragma unroll
  for (int off = 1; off < 64; off <<= 1) {
    s += __shfl_xor(s, off);
    q += __shfl_xor(q, off);
  }
  const float mean = s * (1.0f / 512.0f);
  const float var = q * (1.0f / 512.0f) - mean * mean;
  const float rs = rsqrtf(var + 1e-5f);
  float4 g0 = *(const float4*)(gamma + lane * 8);
  float4 g1 = *(const float4*)(gamma + lane * 8 + 4);
  float4 b0 = *(const float4*)(beta + lane * 8);
  float4 b1 = *(const float4*)(beta + lane * 8 + 4);
  const int bb = row / 3584;
  const int sp = row - bb * 3584;
  size_t drow;
  if (sp < 512)
    drow = (size_t)bb * 512 + sp;
  else if (sp < 1536)
    drow = 8192 + (size_t)bb * 1024 + (sp - 512);
  else
    drow = 24576 + (size_t)bb * 2048 + (sp - 1536);
  bf16x8 ov = {(bf16)((v0.x - mean) * rs * g0.x + b0.x),
               (bf16)((v0.y - mean) * rs * g0.y + b0.y),
               (bf16)((v0.z - mean) * rs * g0.z + b0.z),
               (bf16)((v0.w - mean) * rs * g0.w + b0.w),
               (bf16)((v1.x - mean) * rs * g1.x + b1.x),
               (bf16)((v1.y - mean) * rs * g1.y + b1.y),
               (bf16)((v1.z - mean) * rs * g1.z + b1.z),
               (bf16)((v1.w - mean) * rs * g1.w + b1.w)};
  *(bf16x8*)(h + drow * 512 + lane * 8) = ov;
}

// ---------------------------------------------------------------------------
// QKV GEMM body. n-tiles 0..7 -> Q/K (qk stride 1024); 8..11 -> V' (vt
// transposed per batch). Prepared bias (V part = bv' = bv*Wout).
// ---------------------------------------------------------------------------
__device__ __forceinline__ void qkv_body(const bf16* __restrict__ A,
                                         const bf16* __restrict__ Bt,
                                         const float* __restrict__ bias,
                                         bf16* __restrict__ qk,
                                         bf16* __restrict__ vt, int l2L,
                                         int lgs, bf16 (*smem)[128 * 64]) {
  const int t = threadIdx.x, lane = t & 63, w = t >> 6;
  const int wm = w >> 1, wn = w & 1;
  const int m0 = (lgs / 12) << 7;
  const int n0 = (lgs % 12) << 7;
  const int L = 1 << l2L;

  f32x4 acc[4][4];
#pragma unroll
  for (int i = 0; i < 4; ++i)
#pragma unroll
    for (int j = 0; j < 4; ++j) acc[i][j] = (f32x4)0.0f;

  gemm_core(A, 512, Bt, 512, 8, m0, n0, smem, acc);

  if (n0 < 1024) {
    float* et = (float*)smem;
#pragma unroll
    for (int mi = 0; mi < 4; ++mi) epi_put(et + (mi << 12), acc[mi], lane, wm, wn);
    __syncthreads();
    const int lr = t >> 3, c0l = (t & 7) << 4;
    const int gcol = n0 + c0l;
#pragma unroll
    for (int mi = 0; mi < 4; ++mi) {
      f32x4 v[4];
      epi_get(et + (mi << 12), t, v);
      const int grow = m0 + ((lr >> 4) << 6) + mi * 16 + (lr & 15);
      bf16x8 o0, o1;
#pragma unroll
      for (int j = 0; j < 4; ++j) {
        float4 bv = *(const float4*)(bias + gcol + j * 4);
#pragma unroll
        for (int k = 0; k < 4; ++k) {
          const bf16 val = (bf16)(v[j][k] + ((const float*)&bv)[k]);
          if (j < 2) o0[j * 4 + k] = val;
          else o1[(j - 2) * 4 + k] = val;
        }
      }
      bf16* dst = qk + (size_t)grow * 1024 + gcol;
      *(bf16x8*)dst = o0;
      *(bf16x8*)(dst + 8) = o1;
    }
  } else {
#pragma unroll
    for (int ni = 0; ni < 4; ++ni) {
      const int col = n0 + wn * 64 + ni * 16 + (lane & 15);
      const float bv = bias[col];
#pragma unroll
      for (int mi = 0; mi < 4; ++mi) {
        const int rb = m0 + wm * 64 + mi * 16 + ((lane >> 4) << 2);
        const int d = col - 1024;
        const int bi = rb >> l2L;
        const int kv = rb & (L - 1);
        bf16x4 pk = {(bf16)(acc[mi][ni][0] + bv), (bf16)(acc[mi][ni][1] + bv),
                     (bf16)(acc[mi][ni][2] + bv), (bf16)(acc[mi][ni][3] + bv)};
        *(bf16x4*)(vt + ((size_t)bi * 512 + d) * L + kv) = pk;
      }
    }
  }
}

// Merged QKV: S (768) + M (1536) + L (3072) = 5376 blocks.
__global__ __launch_bounds__(256) void qkv_all(
    const bf16* __restrict__ h, const bf16* __restrict__ wt_s,
    const bf16* __restrict__ wt_m, const bf16* __restrict__ wt_l,
    const float* __restrict__ pb_s, const float* __restrict__ pb_m,
    const float* __restrict__ pb_l, bf16* __restrict__ qk,
    bf16* __restrict__ vt) {
  __shared__ bf16 smem[4][128 * 64];
  const int lg = (blockIdx.x & 7) * (5376 >> 3) + (blockIdx.x >> 3);
  if (lg < 768) {
    qkv_body(h, wt_s, pb_s, qk, vt, 9, lg, smem);
  } else if (lg < 2304) {
    qkv_body(h + 8192ull * 512, wt_m, pb_m, qk + 8192ull * 1024,
             vt + 4194304ull, 10, lg - 768, smem);
  } else {
    qkv_body(h + 24576ull * 512, wt_l, pb_l, qk + 24576ull * 1024,
             vt + 12582912ull, 11, lg - 2304, smem);
  }
}

// ---------------------------------------------------------------------------
// sgemm body: P = exp2(S*scale*log2e) -> Pb + deterministic per-(row,n-tile)
// partial sums into psum (no atomics; max-subtraction safe to skip).
// ---------------------------------------------------------------------------
__device__ __forceinline__ void sgemm_body(const bf16* __restrict__ qkp,
                                           bf16* __restrict__ Cb, int l2L,
                                           int b0, int lgs, float scl2,
                                           float* __restrict__ psum, int psb,
                                           bf16 (*smem)[128 * 64]) {
  const int t = threadIdx.x, lane = t & 63, w = t >> 6;
  const int wm = w >> 1, wn = w & 1;
  const int L = 1 << l2L;
  const int l2nt = l2L - 7;
  const int bi = lgs >> (2 * l2nt);
  const int rem = lgs & ((1 << (2 * l2nt)) - 1);
  const int m0 = (rem >> l2nt) << 7;
  const int n0 = (rem & ((1 << l2nt) - 1)) << 7;

  const bf16* Ab = qkp + (size_t)(b0 + bi) * L * 1024;
  const bf16* Bb = Ab + 512;
  bf16* C = Cb + (size_t)bi * L * L;

  f32x4 acc[4][4];
#pragma unroll
  for (int i = 0; i < 4; ++i)
#pragma unroll
    for (int j = 0; j < 4; ++j) acc[i][j] = (f32x4)0.0f;

  gemm_core(Ab, 1024, Bb, 1024, 8, m0, n0, smem, acc);

  float* et = (float*)smem;
#pragma unroll
  for (int mi = 0; mi < 4; ++mi) epi_put(et + (mi << 12), acc[mi], lane, wm, wn);
  __syncthreads();
  const int lr = t >> 3, c0l = (t & 7) << 4;
  const int tilej = n0 >> 7;
#pragma unroll
  for (int mi = 0; mi < 4; ++mi) {
    f32x4 v[4];
    epi_get(et + (mi << 12), t, v);
    const int grow = m0 + ((lr >> 4) << 6) + mi * 16 + (lr & 15);
    bf16x8 o0, o1;
    float ps = 0.0f;
#pragma unroll
    for (int j = 0; j < 4; ++j)
#pragma unroll
      for (int k = 0; k < 4; ++k) {
        const float e = exp2f(v[j][k] * scl2);
        const bf16 val = (bf16)e;
        ps += (float)val;
        if (j < 2) o0[j * 4 + k] = val;
        else o1[(j - 2) * 4 + k] = val;
      }
    bf16* dst = C + (size_t)grow * L + n0 + c0l;
    *(bf16x8*)dst = o0;
    *(bf16x8*)(dst + 8) = o1;
    ps += __shfl_xor(ps, 1);
    ps += __shfl_xor(ps, 2);
    ps += __shfl_xor(ps, 4);
    if ((t & 7) == 0) psum[((size_t)(psb + bi * L + grow) << 4) + tilej] = ps;
  }
}

// Merged sgemm S (256) + M (1024) = 1280 blocks.
__global__ __launch_bounds__(256) void sgemm_sm(const bf16* __restrict__ qk,
                                                bf16* __restrict__ PS,
                                                bf16* __restrict__ PM,
                                                float scl2,
                                                float* __restrict__ psum) {
  __shared__ bf16 smem[4][128 * 64];
  const int lg = (blockIdx.x & 7) * (1280 >> 3) + (blockIdx.x >> 3);
  if (lg < 256)
    sgemm_body(qk, PS, 9, 0, lg, scl2, psum, 0, smem);
  else
    sgemm_body(qk + 8192ull * 1024, PM, 10, 0, lg - 256, scl2, psum, 8192,
               smem);
}

// Single-scale sgemm (L halves).
__global__ __launch_bounds__(256) void sgemm_one(const bf16* __restrict__ qkp,
                                                 bf16* __restrict__ Cb, int l2L,
                                                 int b0, float scl2, int nblk,
                                                 float* __restrict__ psum) {
  __shared__ bf16 smem[4][128 * 64];
  const int lg = (blockIdx.x & 7) * (nblk >> 3) + (blockIdx.x >> 3);
  sgemm_body(qkp, Cb, l2L, b0, lg, scl2, psum, 0, smem);
}

// ---------------------------------------------------------------------------
// pv body: out[g] = (P * V')/l + bout + x[g]  (fp32 direct to d_out).
// g = (b0+bi)*3584 + seqoff + grow.
// ---------------------------------------------------------------------------
__device__ __forceinline__ void pv_body(const bf16* __restrict__ sb,
                                        const bf16* __restrict__ vtp,
                                        float* __restrict__ out,
                                        const float* __restrict__ x,
                                        const float* __restrict__ bout, int l2L,
                                        int b0, int seqoff, int lgs,
                                        const float* __restrict__ psum, int psb,
                                        bf16 (*smem)[128 * 64]) {
  const int t = threadIdx.x, lane = t & 63, w = t >> 6;
  const int wm = w >> 1, wn = w & 1;
  const int L = 1 << l2L;
  const int l2nt = l2L - 7;
  const int ntile = 1 << l2nt;
  const int bi = lgs >> (l2nt + 2);
  const int rem = lgs & ((1 << (l2nt + 2)) - 1);
  const int m0 = (rem >> 2) << 7;
  const int n0 = (rem & 3) << 7;
  const int b = b0 + bi;

  const bf16* Ab = sb + (size_t)bi * L * L;
  const bf16* Bb = vtp + (size_t)b * 512 * L;

  f32x4 acc[4][4];
#pragma unroll
  for (int i = 0; i < 4; ++i)
#pragma unroll
    for (int j = 0; j < 4; ++j) acc[i][j] = (f32x4)0.0f;

  gemm_core(Ab, L, Bb, L, L >> 6, m0, n0, smem, acc);

  float* et = (float*)smem;
#pragma unroll
  for (int mi = 0; mi < 4; ++mi) epi_put(et + (mi << 12), acc[mi], lane, wm, wn);
  __syncthreads();
  const int lr = t >> 3, c0l = (t & 7) << 4;
  const int gcol = n0 + c0l;
  float4 bvv[4];
#pragma unroll
  for (int j = 0; j < 4; ++j) bvv[j] = *(const float4*)(bout + gcol + j * 4);
#pragma unroll
  for (int mi = 0; mi < 4; ++mi) {
    f32x4 v[4];
    epi_get(et + (mi << 12), t, v);
    const int grow = m0 + ((lr >> 4) << 6) + mi * 16 + (lr & 15);
    const float* pr = psum + ((size_t)(psb + bi * L + grow) << 4);
    float rs = 0.0f;
    for (int j = 0; j < ntile; ++j) rs += pr[j];
    const float inv = 1.0f / rs;
    const size_t g = (size_t)b * 3584 + seqoff + grow;
    const float* xs = x + g * 512 + gcol;
    float* os = out + g * 512 + gcol;
#pragma unroll
    for (int j = 0; j < 4; ++j) {
      float4 xv = *(const float4*)(xs + j * 4);
      float4 ov;
      ov.x = v[j][0] * inv + bvv[j].x + xv.x;
      ov.y = v[j][1] * inv + bvv[j].y + xv.y;
      ov.z = v[j][2] * inv + bvv[j].z + xv.z;
      ov.w = v[j][3] * inv + bvv[j].w + xv.w;
      *(float4*)(os + j * 4) = ov;
    }
  }
}

// Merged pv S (256) + M (512) = 768 blocks.
__global__ __launch_bounds__(256) void pv_sm(
    const bf16* __restrict__ PS, const bf16* __restrict__ PM,
    const bf16* __restrict__ vt, float* __restrict__ out,
    const float* __restrict__ x, const float* __restrict__ bout,
    const float* __restrict__ psum) {
  __shared__ bf16 smem[4][128 * 64];
  const int lg = (blockIdx.x & 7) * (768 >> 3) + (blockIdx.x >> 3);
  if (lg < 256)
    pv_body(PS, vt, out, x, bout, 9, 0, 0, lg, psum, 0, smem);
  else
    pv_body(PM, vt + 4194304ull, out, x, bout, 10, 0, 512, lg - 256, psum,
            8192, smem);
}

// Single-scale pv (L halves).
__global__ __launch_bounds__(256) void pv_one(const bf16* __restrict__ sb,
                                              const bf16* __restrict__ vtp,
                                              float* __restrict__ out,
                                              const float* __restrict__ x,
                                              const float* __restrict__ bout,
                                              int l2L, int b0, int seqoff,
                                              int nblk,
                                              const float* __restrict__ psum) {
  __shared__ bf16 smem[4][128 * 64];
  const int lg = (blockIdx.x & 7) * (nblk >> 3) + (blockIdx.x >> 3);
  pv_body(sb, vtp, out, x, bout, l2L, b0, seqoff, lg, psum, 0, smem);
}

// ---------------------------------------------------------------------------
extern "C" void kernel_launch(void* const* d_in, const int* in_sizes, int n_in,
                              void* d_out, int out_size, void* d_ws,
                              size_t ws_size, hipStream_t stream) {
  const float* x = (const float*)d_in[0];
  const float* gamma = (const float*)d_in[1];
  const float* beta = (const float*)d_in[2];
  const float* Wq_s = (const float*)d_in[3];
  const float* bq_s = (const float*)d_in[4];
  const float* Wq_m = (const float*)d_in[5];
  const float* bq_m = (const float*)d_in[6];
  const float* Wq_l = (const float*)d_in[7];
  const float* bq_l = (const float*)d_in[8];
  const float* Wout = (const float*)d_in[9];
  const float* bout = (const float*)d_in[10];
  float* out = (float*)d_out;

  char* ws = (char*)d_ws;
  bf16* h = (bf16*)(ws);                      // 57344 x 512; later P region
  bf16* qk = (bf16*)(ws + 58720256ull);       // 57344 x 1024
  bf16* vt = (bf16*)(ws + 176160768ull);      // 57344 x 512 (V'^T per batch)
  bf16* wt_s = (bf16*)(ws + 234881024ull);
  bf16* wt_m = (bf16*)(ws + 236453888ull);
  bf16* wt_l = (bf16*)(ws + 238026752ull);
  bf16* wt_o = (bf16*)(ws + 239599616ull);
  float* psum = (float*)(ws + 240123904ull);  // 24576 rows x 16 x fp32 (1.6MB)

  // d_out tail scratch (dead before pv writes): Bv + prepared biases.
  char* od = (char*)d_out;
  bf16* Bv_s = (bf16*)(od + 110000128ull);    // 3 x 512KB
  bf16* Bv_m = Bv_s + 262144;
  bf16* Bv_l = Bv_m + 262144;
  float* pb_s = (float*)(od + 111573504ull);  // 3 x 1536 fp32
  float* pb_m = pb_s + 1536;
  float* pb_l = pb_m + 1536;

  transpose_all<<<2560, dim3(32, 8), 0, stream>>>(Wq_s, Wq_m, Wq_l, Wout, wt_s,
                                                  wt_m, wt_l, wt_o);
  conv_v<<<768, 256, 0, stream>>>(Wq_s, Wq_m, Wq_l, Bv_s, Bv_m, Bv_l);
  wprep<<<48, 256, 0, stream>>>(wt_o, Bv_s, Bv_m, Bv_l, wt_s, wt_m, wt_l);
  bias_prep<<<3, 512, 0, stream>>>(bq_s, bq_m, bq_l, Wout, pb_s, pb_m, pb_l);

  ln_kernel<<<14336, 256, 0, stream>>>(x, gamma, beta, h);

  qkv_all<<<5376, 256, 0, stream>>>(h, wt_s, wt_m, wt_l, pb_s, pb_m, pb_l, qk,
                                    vt);

  const float scale = 0.04419417382415922f;      // 512^-0.5
  const float scl2 = scale * 1.44269504088896f;  // * log2(e)

  // P buffers: S (8.4MB) + M (33.6MB) both in h region (42MB <= 58.7MB).
  bf16* PS = h;
  bf16* PM = h + 4194304ull;  // 8.4MB / 2B

  // S+M: merged sgemm (1280) then merged pv (768).
  sgemm_sm<<<1280, 256, 0, stream>>>(qk, PS, PM, scl2, psum);
  pv_sm<<<768, 256, 0, stream>>>(PS, PM, vt, out, x, bout, psum);

  // L: two halves of 8 batches. P-L (67.1MB) spans h (58.7MB, dead after
  // pv_sm) + first 8.4MB of qk-S (dead after sgemm_sm). Contiguous at ws+0.
  bf16* PL = h;
  for (int b0 = 0; b0 < 16; b0 += 8) {
    sgemm_one<<<2048, 256, 0, stream>>>(qk + 24576ull * 1024, PL, 11, b0, scl2,
                                        2048, psum);
    pv_one<<<512, 256, 0, stream>>>(PL, vt + 12582912ull, out, x, bout, 11, b0,
                                    1536, 512, psum);
  }
}